// Round 3
// baseline (865.408 us; speedup 1.0000x reference)
//
#include <hip/hip_runtime.h>

#define NQ 4
#define NL 4

// ---------------------------------------------------------------------------
// Precompute kernel (verified R0/R1): build
// V[16][16][2] = U * diag((-i)^popcount(k)), U = full SEL unitary.
// ---------------------------------------------------------------------------
__global__ __launch_bounds__(64) void qnn_precompute(
    const float* __restrict__ w,   // [4][4][3] (phi, theta, omega)
    float* __restrict__ V)         // [16][16][2] interleaved (re, im)
{
  int k = threadIdx.x;
  if (k >= 16) return;
  float pr[16], pi[16];
#pragma unroll
  for (int j = 0; j < 16; ++j) { pr[j] = (j == k) ? 1.f : 0.f; pi[j] = 0.f; }

  const int ranges[4] = {1, 2, 3, 1};
#pragma unroll
  for (int l = 0; l < NL; ++l) {
#pragma unroll
    for (int q = 0; q < NQ; ++q) {
      float phi = w[l*12 + q*3 + 0];
      float th  = w[l*12 + q*3 + 1];
      float om  = w[l*12 + q*3 + 2];
      float st, ct;  __sincosf(0.5f*th, &st, &ct);
      float spo, cpo; __sincosf(0.5f*(phi+om), &spo, &cpo);
      float smo, cmo; __sincosf(0.5f*(phi-om), &smo, &cmo);
      float ar = cpo*ct,  ai = -spo*ct;
      float br = -cmo*st, bi = -smo*st;
      float dr = cmo*st,  di = -smo*st;
      float er = cpo*ct,  ei = spo*ct;
      int m = 8 >> q;
#pragma unroll
      for (int i0 = 0; i0 < 16; ++i0) {
        if (i0 & m) continue;
        int i1 = i0 | m;
        float x0r = pr[i0], x0i = pi[i0], x1r = pr[i1], x1i = pi[i1];
        pr[i0] = ar*x0r - ai*x0i + br*x1r - bi*x1i;
        pi[i0] = ar*x0i + ai*x0r + br*x1i + bi*x1r;
        pr[i1] = dr*x0r - di*x0i + er*x1r - ei*x1i;
        pi[i1] = dr*x0i + di*x0r + er*x1i + ei*x1r;
      }
    }
    int r = ranges[l];
#pragma unroll
    for (int q = 0; q < NQ; ++q) {
      int mc = 8 >> q;
      int mt = 8 >> ((q + r) & 3);
#pragma unroll
      for (int i = 0; i < 16; ++i) {
        if ((i & mc) && !(i & mt)) {
          int i2 = i | mt;
          float tr = pr[i]; pr[i] = pr[i2]; pr[i2] = tr;
          float ti = pi[i]; pi[i] = pi[i2]; pi[i2] = ti;
        }
      }
    }
  }

  int pc = __popc(k) & 3;
#pragma unroll
  for (int j = 0; j < 16; ++j) {
    float re = pr[j], im = pi[j], re2, im2;
    if      (pc == 0) { re2 =  re; im2 =  im; }
    else if (pc == 1) { re2 =  im; im2 = -re; }
    else if (pc == 2) { re2 = -re; im2 = -im; }
    else              { re2 = -im; im2 =  re; }
    V[(j*16 + k)*2 + 0] = re2;
    V[(j*16 + k)*2 + 1] = im2;
  }
}

// ---------------------------------------------------------------------------
// Main kernel: 4 samples per thread. Each V float4 (2 complex entries) is
// read once from LDS and feeds 16 FMA (4 samples x re/im x 2 entries),
// amortizing the LDS pipe cost (~12 cyc per ds_read_b128) 4x vs R1.
// Output staged via a reused 256-sample LDS chunk (4 chunks/block).
// ---------------------------------------------------------------------------
__global__ __launch_bounds__(256, 4) void qnn_main(
    const float4* __restrict__ x,     // [B] of float4  (B,4)
    const float4* __restrict__ V4,    // [16][16][2] as float4[128]
    const float*  __restrict__ fcw,   // [10][4]
    const float*  __restrict__ fcb,   // [10]
    float*        __restrict__ out,   // [B*10]
    int nB)
{
  __shared__ float sV[512];           // 2 KB
  __shared__ float so[256 * 11];      // 11.25 KB, stride-11 pad, reused 4x

  int t = threadIdx.x;
  if (t < 128) ((float4*)sV)[t] = V4[t];

  int base = blockIdx.x * 1024;

  float r[4][16];
  float zz[4][4];

#pragma unroll
  for (int s = 0; s < 4; ++s) {
    int b = base + t + s * 256;
    float4 xv = (b < nB) ? x[b] : make_float4(0.f, 0.f, 0.f, 0.f);
    float s0, c0, s1, c1, s2, c2, s3, c3;
    __sincosf(0.5f * xv.x, &s0, &c0);
    __sincosf(0.5f * xv.y, &s1, &c1);
    __sincosf(0.5f * xv.z, &s2, &c2);
    __sincosf(0.5f * xv.w, &s3, &c3);
    float w01[4];
    w01[0] = c0 * c1; w01[1] = c0 * s1; w01[2] = s0 * c1; w01[3] = s0 * s1;
#pragma unroll
    for (int i = 0; i < 4; ++i) {
      float a = w01[i] * c2, bb = w01[i] * s2;
      r[s][4*i + 0] = a  * c3;
      r[s][4*i + 1] = a  * s3;
      r[s][4*i + 2] = bb * c3;
      r[s][4*i + 3] = bb * s3;
    }
    zz[s][0] = 0.f; zz[s][1] = 0.f; zz[s][2] = 0.f; zz[s][3] = 0.f;
  }

  __syncthreads();    // sV ready

#pragma unroll
  for (int j = 0; j < 16; ++j) {
    float re[4] = {0.f, 0.f, 0.f, 0.f};
    float im[4] = {0.f, 0.f, 0.f, 0.f};
#pragma unroll
    for (int q = 0; q < 8; ++q) {
      // (Re V[j][2q], Im V[j][2q], Re V[j][2q+1], Im V[j][2q+1])
      float4 v = *(const float4*)(sV + j * 32 + q * 4);
#pragma unroll
      for (int s = 0; s < 4; ++s) {
        re[s] = fmaf(v.x, r[s][2*q + 0], re[s]);
        im[s] = fmaf(v.y, r[s][2*q + 0], im[s]);
        re[s] = fmaf(v.z, r[s][2*q + 1], re[s]);
        im[s] = fmaf(v.w, r[s][2*q + 1], im[s]);
      }
    }
#pragma unroll
    for (int s = 0; s < 4; ++s) {
      float p = fmaf(re[s], re[s], im[s] * im[s]);
      zz[s][0] += (j & 8) ? -p : p;
      zz[s][1] += (j & 4) ? -p : p;
      zz[s][2] += (j & 2) ? -p : p;
      zz[s][3] += (j & 1) ? -p : p;
    }
  }

  int lim = nB * 10;
#pragma unroll
  for (int s = 0; s < 4; ++s) {
    __syncthreads();  // protect so[] reuse
#pragma unroll
    for (int o = 0; o < 10; ++o) {
      float v = fcb[o];
      v = fmaf(fcw[o*4 + 0], zz[s][0], v);
      v = fmaf(fcw[o*4 + 1], zz[s][1], v);
      v = fmaf(fcw[o*4 + 2], zz[s][2], v);
      v = fmaf(fcw[o*4 + 3], zz[s][3], v);
      so[t * 11 + o] = v;
    }
    __syncthreads();
    int cbase = (base + s * 256) * 10;
#pragma unroll
    for (int i = 0; i < 10; ++i) {
      int f = t + i * 256;
      int g = cbase + f;
      if (g < lim) {
        int s2 = f / 10;
        int o  = f - s2 * 10;
        out[g] = so[s2 * 11 + o];
      }
    }
  }
}

extern "C" void kernel_launch(void* const* d_in, const int* in_sizes, int n_in,
                              void* d_out, int out_size, void* d_ws, size_t ws_size,
                              hipStream_t stream) {
  const float* x   = (const float*)d_in[0];
  const float* w   = (const float*)d_in[1];
  const float* fcw = (const float*)d_in[2];
  const float* fcb = (const float*)d_in[3];
  float* out = (float*)d_out;
  float* V   = (float*)d_ws;        // 16*16*2 floats = 2 KB
  int nB = in_sizes[0] / 4;

  hipLaunchKernelGGL(qnn_precompute, dim3(1), dim3(64), 0, stream, w, V);
  int nblk = (nB + 1023) / 1024;
  hipLaunchKernelGGL(qnn_main, dim3(nblk), dim3(256), 0, stream,
                     (const float4*)x, (const float4*)V, fcw, fcb, out, nB);
}

// Round 4
// 29.857 us; speedup vs baseline: 28.9853x; 28.9853x over previous
//
#include <hip/hip_runtime.h>

#define NQ 4
#define NL 4

typedef _Float16 f16x8 __attribute__((ext_vector_type(8)));
typedef float f32x16 __attribute__((ext_vector_type(16)));

// ---------------------------------------------------------------------------
// Precompute: M[32][16] f32, rows 0-15 = Re(V), rows 16-31 = Im(V), where
// V = U * diag((-i)^popcount(k)), U = full 4-layer SEL unitary.
// Thread k (0..15) pushes basis column k through the gates.
// ---------------------------------------------------------------------------
__global__ __launch_bounds__(64) void qnn_precompute(
    const float* __restrict__ w,   // [4][4][3] (phi, theta, omega)
    float* __restrict__ M)         // [32][16]
{
  int k = threadIdx.x;
  if (k >= 16) return;
  float pr[16], pi[16];
#pragma unroll
  for (int j = 0; j < 16; ++j) { pr[j] = (j == k) ? 1.f : 0.f; pi[j] = 0.f; }

  const int ranges[4] = {1, 2, 3, 1};
#pragma unroll
  for (int l = 0; l < NL; ++l) {
#pragma unroll
    for (int q = 0; q < NQ; ++q) {
      float phi = w[l*12 + q*3 + 0];
      float th  = w[l*12 + q*3 + 1];
      float om  = w[l*12 + q*3 + 2];
      float st, ct;  __sincosf(0.5f*th, &st, &ct);
      float spo, cpo; __sincosf(0.5f*(phi+om), &spo, &cpo);
      float smo, cmo; __sincosf(0.5f*(phi-om), &smo, &cmo);
      float ar = cpo*ct,  ai = -spo*ct;
      float br = -cmo*st, bi = -smo*st;
      float dr = cmo*st,  di = -smo*st;
      float er = cpo*ct,  ei = spo*ct;
      int m = 8 >> q;
#pragma unroll
      for (int i0 = 0; i0 < 16; ++i0) {
        if (i0 & m) continue;
        int i1 = i0 | m;
        float x0r = pr[i0], x0i = pi[i0], x1r = pr[i1], x1i = pi[i1];
        pr[i0] = ar*x0r - ai*x0i + br*x1r - bi*x1i;
        pi[i0] = ar*x0i + ai*x0r + br*x1i + bi*x1r;
        pr[i1] = dr*x0r - di*x0i + er*x1r - ei*x1i;
        pi[i1] = dr*x0i + di*x0r + er*x1i + ei*x1r;
      }
    }
    int r = ranges[l];
#pragma unroll
    for (int q = 0; q < NQ; ++q) {
      int mc = 8 >> q;
      int mt = 8 >> ((q + r) & 3);
#pragma unroll
      for (int i = 0; i < 16; ++i) {
        if ((i & mc) && !(i & mt)) {
          int i2 = i | mt;
          float tr = pr[i]; pr[i] = pr[i2]; pr[i2] = tr;
          float ti = pi[i]; pi[i] = pi[i2]; pi[i2] = ti;
        }
      }
    }
  }

  int pc = __popc(k) & 3;
#pragma unroll
  for (int j = 0; j < 16; ++j) {
    float re = pr[j], im = pi[j], re2, im2;
    if      (pc == 0) { re2 =  re; im2 =  im; }
    else if (pc == 1) { re2 =  im; im2 = -re; }
    else if (pc == 2) { re2 = -re; im2 = -im; }
    else              { re2 = -im; im2 =  re; }
    M[j*16 + k]        = re2;
    M[(16 + j)*16 + k] = im2;
  }
}

// ---------------------------------------------------------------------------
// Main: per wave-iteration 32 samples via one 32x32x16 f16 MFMA pair
// (split-A for precision). A-fragment (M) lives in 8 VGPRs for the whole
// kernel -> zero per-sample coefficient traffic.
//   A[row][k]: row = lane&31, k = (lane>>5)*8 + i   (rows: 16 re + 16 im)
//   B[k][col]: col = lane&31 (sample), k = (lane>>5)*8 + i  (r-vector)
//   C: col = lane&31, row = (reg&3) + 8*(reg>>2) + 4*(lane>>5)
// Lane pair (L, L+32) holds sample L&31's 16 (re,im) pairs -> local probs,
// partial signed z-sums, one shfl_xor(32) combine, 5 fc outputs per lane.
// ---------------------------------------------------------------------------
__global__ __launch_bounds__(256) void qnn_main(
    const float4* __restrict__ x,     // [B] float4
    const float*  __restrict__ M,     // [32][16]
    const float*  __restrict__ fcw,   // [10][4]
    const float*  __restrict__ fcb,   // [10]
    float*        __restrict__ out,   // [B*10]
    int nB, int iters)
{
  __shared__ float so[128 * 11];      // 5.6 KB staging, reused per iter

  int t    = threadIdx.x;
  int lane = t & 63;
  int wv   = t >> 6;                  // wave 0..3
  int col  = lane & 31;
  int hi   = lane >> 5;               // 0/1
  int k0   = hi * 8;

  // Load A fragment once: row = lane&31, k = k0..k0+7 (contiguous in M)
  f16x8 Ahi, Alo;
#pragma unroll
  for (int i = 0; i < 8; ++i) {
    float v = M[(lane & 31) * 16 + k0 + i];
    _Float16 h = (_Float16)v;
    Ahi[i] = h;
    Alo[i] = (_Float16)(v - (float)h);
  }

  int sbase0 = blockIdx.x * (iters * 128);
  int lim = nB * 10;

  for (int it = 0; it < iters; ++it) {
    int s = sbase0 + it * 128 + wv * 32 + col;
    int sc = (s < nB) ? s : 0;        // clamp; tail stores are guarded
    float4 xv = x[sc];

    float s0, c0, s1, c1, s2, c2, s3, c3;
    __sincosf(0.5f * xv.x, &s0, &c0);
    __sincosf(0.5f * xv.y, &s1, &c1);
    __sincosf(0.5f * xv.z, &s2, &c2);
    __sincosf(0.5f * xv.w, &s3, &c3);

    // B fragment: this lane supplies r[k0..k0+7] of its sample.
    // r[m*4+n] = w01[m] * w23[n]; lane half selects m in {0,1} or {2,3}.
    float cs0 = hi ? s0 : c0;
    float a0 = cs0 * c1, a1 = cs0 * s1;
    float w0 = c2 * c3, w1 = c2 * s3, w2 = s2 * c3, w3 = s2 * s3;
    f16x8 Bf;
    Bf[0] = (_Float16)(a0 * w0); Bf[1] = (_Float16)(a0 * w1);
    Bf[2] = (_Float16)(a0 * w2); Bf[3] = (_Float16)(a0 * w3);
    Bf[4] = (_Float16)(a1 * w0); Bf[5] = (_Float16)(a1 * w1);
    Bf[6] = (_Float16)(a1 * w2); Bf[7] = (_Float16)(a1 * w3);

    f32x16 acc = {0.f,0.f,0.f,0.f,0.f,0.f,0.f,0.f,
                  0.f,0.f,0.f,0.f,0.f,0.f,0.f,0.f};
    acc = __builtin_amdgcn_mfma_f32_32x32x16_f16(Ahi, Bf, acc, 0, 0, 0);
    acc = __builtin_amdgcn_mfma_f32_32x32x16_f16(Alo, Bf, acc, 0, 0, 0);

    // probs: reg jj (re) pairs with jj+8 (im), j = (jj&3) + 8*(jj>>2) + 4*hi
    float p0 = fmaf(acc[0], acc[0], acc[8]  * acc[8]);
    float p1 = fmaf(acc[1], acc[1], acc[9]  * acc[9]);
    float p2 = fmaf(acc[2], acc[2], acc[10] * acc[10]);
    float p3 = fmaf(acc[3], acc[3], acc[11] * acc[11]);
    float p4 = fmaf(acc[4], acc[4], acc[12] * acc[12]);
    float p5 = fmaf(acc[5], acc[5], acc[13] * acc[13]);
    float p6 = fmaf(acc[6], acc[6], acc[14] * acc[14]);
    float p7 = fmaf(acc[7], acc[7], acc[15] * acc[15]);

    float q0 = p0 + p1, q1 = p2 + p3, q2 = p4 + p5, q3 = p6 + p7;
    float tlo = q0 + q1, thi = q2 + q3;
    float z0p = tlo - thi;                    // sign: j&8 = 8*(jj>>2)
    float tot = tlo + thi;
    float z1p = hi ? -tot : tot;              // sign: j&4 = 4*hi
    float z2p = (q0 + q2) - (q1 + q3);        // sign: j&2 = jj&2
    float r0 = p0 + p2, r1 = p1 + p3, r2 = p4 + p6, r3 = p5 + p7;
    float z3p = (r0 + r2) - (r1 + r3);        // sign: j&1 = jj&1

    float z0 = z0p + __shfl_xor(z0p, 32, 64);
    float z1 = z1p + __shfl_xor(z1p, 32, 64);
    float z2 = z2p + __shfl_xor(z2p, 32, 64);
    float z3 = z3p + __shfl_xor(z3p, 32, 64);

    // fc: lane half computes 5 of the 10 outputs for its sample
    int sl = wv * 32 + col;
#pragma unroll
    for (int o = 0; o < 5; ++o) {
      int oo = 5 * hi + o;
      float v = fcb[oo];
      v = fmaf(fcw[oo*4 + 0], z0, v);
      v = fmaf(fcw[oo*4 + 1], z1, v);
      v = fmaf(fcw[oo*4 + 2], z2, v);
      v = fmaf(fcw[oo*4 + 3], z3, v);
      so[sl * 11 + oo] = v;
    }
    __syncthreads();

    // coalesced copy of this iteration's 1280 floats
    int gb = (sbase0 + it * 128) * 10;
#pragma unroll
    for (int i = 0; i < 5; ++i) {
      int f = t + i * 256;
      int g = gb + f;
      if (g < lim) {
        int s2 = f / 10;
        out[g] = so[s2 * 11 + (f - s2 * 10)];
      }
    }
    __syncthreads();
  }
}

extern "C" void kernel_launch(void* const* d_in, const int* in_sizes, int n_in,
                              void* d_out, int out_size, void* d_ws, size_t ws_size,
                              hipStream_t stream) {
  const float* x   = (const float*)d_in[0];
  const float* w   = (const float*)d_in[1];
  const float* fcw = (const float*)d_in[2];
  const float* fcb = (const float*)d_in[3];
  float* out = (float*)d_out;
  float* M   = (float*)d_ws;        // 32*16 floats = 2 KB
  int nB = in_sizes[0] / 4;

  hipLaunchKernelGGL(qnn_precompute, dim3(1), dim3(64), 0, stream, w, M);

  const int iters = 4;              // 512 samples per block
  int nblk = (nB + 128 * iters - 1) / (128 * iters);
  hipLaunchKernelGGL(qnn_main, dim3(nblk), dim3(256), 0, stream,
                     (const float4*)x, M, fcw, fcb, out, nB, iters);
}

// Round 5
// 29.782 us; speedup vs baseline: 29.0581x; 1.0025x over previous
//
#include <hip/hip_runtime.h>

#define NQ 4
#define NL 4

typedef _Float16 f16x8 __attribute__((ext_vector_type(8)));
typedef float f32x16 __attribute__((ext_vector_type(16)));

// ---------------------------------------------------------------------------
// Precompute (1 block, 64 thr): writes to ws (_Float16):
//   Mh[32][16] @0, Ml[32][16] @512   : split-f16 of M = [Re V; Im V],
//       V = U * diag((-i)^popcount(k)), U = full 4-layer SEL unitary
//   Gh[32][16] @1024, Gl[32][16] @1536 : split-f16 of Gp, where
//       Gp[o][k] = sum_w fcw[o][w]*sgn_w(j(k)), j(k)=(k&3)+8*((k>>2)&1)+4*(k>>3)
//       rows 10..31 zero.
// ---------------------------------------------------------------------------
__global__ __launch_bounds__(64) void qnn_precompute(
    const float* __restrict__ w,     // [4][4][3]
    const float* __restrict__ fcw,   // [10][4]
    _Float16* __restrict__ ws)
{
  int k = threadIdx.x;

  if (k < 16) {
    float pr[16], pi[16];
#pragma unroll
    for (int j = 0; j < 16; ++j) { pr[j] = (j == k) ? 1.f : 0.f; pi[j] = 0.f; }

    const int ranges[4] = {1, 2, 3, 1};
#pragma unroll
    for (int l = 0; l < NL; ++l) {
#pragma unroll
      for (int q = 0; q < NQ; ++q) {
        float phi = w[l*12 + q*3 + 0];
        float th  = w[l*12 + q*3 + 1];
        float om  = w[l*12 + q*3 + 2];
        float st, ct;  __sincosf(0.5f*th, &st, &ct);
        float spo, cpo; __sincosf(0.5f*(phi+om), &spo, &cpo);
        float smo, cmo; __sincosf(0.5f*(phi-om), &smo, &cmo);
        float ar = cpo*ct,  ai = -spo*ct;
        float br = -cmo*st, bi = -smo*st;
        float dr = cmo*st,  di = -smo*st;
        float er = cpo*ct,  ei = spo*ct;
        int m = 8 >> q;
#pragma unroll
        for (int i0 = 0; i0 < 16; ++i0) {
          if (i0 & m) continue;
          int i1 = i0 | m;
          float x0r = pr[i0], x0i = pi[i0], x1r = pr[i1], x1i = pi[i1];
          pr[i0] = ar*x0r - ai*x0i + br*x1r - bi*x1i;
          pi[i0] = ar*x0i + ai*x0r + br*x1i + bi*x1r;
          pr[i1] = dr*x0r - di*x0i + er*x1r - ei*x1i;
          pi[i1] = dr*x0i + di*x0r + er*x1i + ei*x1r;
        }
      }
      int r = ranges[l];
#pragma unroll
      for (int q = 0; q < NQ; ++q) {
        int mc = 8 >> q;
        int mt = 8 >> ((q + r) & 3);
#pragma unroll
        for (int i = 0; i < 16; ++i) {
          if ((i & mc) && !(i & mt)) {
            int i2 = i | mt;
            float tr = pr[i]; pr[i] = pr[i2]; pr[i2] = tr;
            float ti = pi[i]; pi[i] = pi[i2]; pi[i2] = ti;
          }
        }
      }
    }

    int pc = __popc(k) & 3;
#pragma unroll
    for (int j = 0; j < 16; ++j) {
      float re = pr[j], im = pi[j], re2, im2;
      if      (pc == 0) { re2 =  re; im2 =  im; }
      else if (pc == 1) { re2 =  im; im2 = -re; }
      else if (pc == 2) { re2 = -re; im2 = -im; }
      else              { re2 = -im; im2 =  re; }
      _Float16 h;
      h = (_Float16)re2;
      ws[j*16 + k]            = h;                               // Mh re
      ws[512 + j*16 + k]      = (_Float16)(re2 - (float)h);      // Ml re
      h = (_Float16)im2;
      ws[(16 + j)*16 + k]     = h;                               // Mh im
      ws[512 + (16 + j)*16 + k] = (_Float16)(im2 - (float)h);    // Ml im
    }
  }

  // G matrix rows (threads 0..31 handle rows 0..31; rows >=10 are zero)
  if (k < 32) {
#pragma unroll
    for (int kk = 0; kk < 16; ++kk) {
      float g = 0.f;
      if (k < 10) {
        int j = (kk & 3) + 8 * ((kk >> 2) & 1) + 4 * (kk >> 3);
        g = fcw[k*4 + 0] * ((j & 8) ? -1.f : 1.f)
          + fcw[k*4 + 1] * ((j & 4) ? -1.f : 1.f)
          + fcw[k*4 + 2] * ((j & 2) ? -1.f : 1.f)
          + fcw[k*4 + 3] * ((j & 1) ? -1.f : 1.f);
      }
      _Float16 h = (_Float16)g;
      ws[1024 + k*16 + kk] = h;
      ws[1536 + k*16 + kk] = (_Float16)(g - (float)h);
    }
  }
}

// ---------------------------------------------------------------------------
// Main: per wave-iter 32 samples.
//   MFMA#1 (x2 split-A): psi[32] = M[32x16] . r[16]   (A = M, resident VGPRs)
//   probs per lane-pair, cast to f16 (B-layout matches automatically)
//   MFMA#2 (x2 split-A): out[10] = Gp[10x16] . p[16] (+bias in acc-init)
//   direct predicated float2 stores (wave writes a contiguous 1280B region)
// ---------------------------------------------------------------------------
__global__ __launch_bounds__(256) void qnn_main(
    const float4* __restrict__ x,     // [B]
    const f16x8*  __restrict__ W8,    // ws: Mh|Ml|Gh|Gl, 64 f16x8 each
    const float*  __restrict__ fcb,   // [10]
    float*        __restrict__ out,   // [B*10]
    int nB, int iters)
{
  int t    = threadIdx.x;
  int lane = t & 63;
  int wv   = t >> 6;
  int col  = lane & 31;
  int hi   = lane >> 5;

  int fr = (lane & 31) * 2 + hi;
  f16x8 Ahi = W8[fr];
  f16x8 Alo = W8[64 + fr];
  f16x8 Ghi = W8[128 + fr];
  f16x8 Glo = W8[192 + fr];

  // bias regs: acc2 rows for this lane: hi=0 -> {0,1,2,3,8,9}, hi=1 -> {4,5,6,7}
  int o0 = hi * 4;
  float b0 = fcb[o0 + 0], b1 = fcb[o0 + 1], b2 = fcb[o0 + 2], b3 = fcb[o0 + 3];
  float b4 = hi ? 0.f : fcb[8];
  float b5 = hi ? 0.f : fcb[9];

  int sbase0 = blockIdx.x * (iters * 128);

  for (int it = 0; it < iters; ++it) {
    int s  = sbase0 + it * 128 + wv * 32 + col;
    int sc = (s < nB) ? s : 0;
    float4 xv = x[sc];

    // trig: cs0 = hi ? sin(x0/2) : cos(x0/2)  (one transcendental via +pi/2)
    float cs0 = __sinf(fmaf(0.5f, xv.x, hi ? 0.f : 1.57079632679f));
    float s1, c1, s2, c2, s3, c3;
    __sincosf(0.5f * xv.y, &s1, &c1);
    __sincosf(0.5f * xv.z, &s2, &c2);
    __sincosf(0.5f * xv.w, &s3, &c3);

    float a0 = cs0 * c1, a1 = cs0 * s1;
    float w0 = c2 * c3, w1 = c2 * s3, w2 = s2 * c3, w3 = s2 * s3;
    f16x8 Bf;
    Bf[0] = (_Float16)(a0 * w0); Bf[1] = (_Float16)(a0 * w1);
    Bf[2] = (_Float16)(a0 * w2); Bf[3] = (_Float16)(a0 * w3);
    Bf[4] = (_Float16)(a1 * w0); Bf[5] = (_Float16)(a1 * w1);
    Bf[6] = (_Float16)(a1 * w2); Bf[7] = (_Float16)(a1 * w3);

    f32x16 acc = {0.f,0.f,0.f,0.f,0.f,0.f,0.f,0.f,
                  0.f,0.f,0.f,0.f,0.f,0.f,0.f,0.f};
    acc = __builtin_amdgcn_mfma_f32_32x32x16_f16(Ahi, Bf, acc, 0, 0, 0);
    acc = __builtin_amdgcn_mfma_f32_32x32x16_f16(Alo, Bf, acc, 0, 0, 0);

    // probs: reg jj (re) pairs with reg jj+8 (im)
    f16x8 Bp;
    Bp[0] = (_Float16)fmaf(acc[0], acc[0], acc[8]  * acc[8]);
    Bp[1] = (_Float16)fmaf(acc[1], acc[1], acc[9]  * acc[9]);
    Bp[2] = (_Float16)fmaf(acc[2], acc[2], acc[10] * acc[10]);
    Bp[3] = (_Float16)fmaf(acc[3], acc[3], acc[11] * acc[11]);
    Bp[4] = (_Float16)fmaf(acc[4], acc[4], acc[12] * acc[12]);
    Bp[5] = (_Float16)fmaf(acc[5], acc[5], acc[13] * acc[13]);
    Bp[6] = (_Float16)fmaf(acc[6], acc[6], acc[14] * acc[14]);
    Bp[7] = (_Float16)fmaf(acc[7], acc[7], acc[15] * acc[15]);

    f32x16 acc2 = {b0, b1, b2, b3, b4, b5, 0.f, 0.f,
                   0.f, 0.f, 0.f, 0.f, 0.f, 0.f, 0.f, 0.f};
    acc2 = __builtin_amdgcn_mfma_f32_32x32x16_f16(Ghi, Bp, acc2, 0, 0, 0);
    acc2 = __builtin_amdgcn_mfma_f32_32x32x16_f16(Glo, Bp, acc2, 0, 0, 0);

    if (s < nB) {
      float* op = out + (size_t)s * 10 + o0;   // 8B-aligned (40s + 16*hi)
      float2 v01; v01.x = acc2[0]; v01.y = acc2[1];
      float2 v23; v23.x = acc2[2]; v23.y = acc2[3];
      *(float2*)(op + 0) = v01;
      *(float2*)(op + 2) = v23;
      if (!hi) {
        float2 v89; v89.x = acc2[4]; v89.y = acc2[5];
        *(float2*)(out + (size_t)s * 10 + 8) = v89;
      }
    }
  }
}

extern "C" void kernel_launch(void* const* d_in, const int* in_sizes, int n_in,
                              void* d_out, int out_size, void* d_ws, size_t ws_size,
                              hipStream_t stream) {
  const float* x   = (const float*)d_in[0];
  const float* w   = (const float*)d_in[1];
  const float* fcw = (const float*)d_in[2];
  const float* fcb = (const float*)d_in[3];
  float* out = (float*)d_out;
  _Float16* ws = (_Float16*)d_ws;   // 2048 f16 = 4 KB
  int nB = in_sizes[0] / 4;

  hipLaunchKernelGGL(qnn_precompute, dim3(1), dim3(64), 0, stream, w, fcw, ws);

  const int iters = 4;              // 512 samples per block
  int nblk = (nB + 128 * iters - 1) / (128 * iters);
  hipLaunchKernelGGL(qnn_main, dim3(nblk), dim3(256), 0, stream,
                     (const float4*)x, (const f16x8*)ws, fcb, out, nB, iters);
}

// Round 6
// 29.169 us; speedup vs baseline: 29.6691x; 1.0210x over previous
//
#include <hip/hip_runtime.h>

#define NQ 4
#define NL 4

typedef _Float16 f16x8 __attribute__((ext_vector_type(8)));
typedef float f32x16 __attribute__((ext_vector_type(16)));

// ---------------------------------------------------------------------------
// Precompute (1 block, 64 thr): writes to ws (_Float16):
//   Mh[32][16] @0, Ml[32][16] @512   : split-f16 of M = [Re V; Im V],
//       V = U * diag((-i)^popcount(k)), U = full 4-layer SEL unitary
//   Gh[32][16] @1024, Gl[32][16] @1536 : split-f16 of Gp, where
//       Gp[o][k] = sum_w fcw[o][w]*sgn_w(j(k)), j(k)=(k&3)+8*((k>>2)&1)+4*(k>>3)
//       rows 10..31 zero.
// ---------------------------------------------------------------------------
__global__ __launch_bounds__(64) void qnn_precompute(
    const float* __restrict__ w,     // [4][4][3]
    const float* __restrict__ fcw,   // [10][4]
    _Float16* __restrict__ ws)
{
  int k = threadIdx.x;

  if (k < 16) {
    float pr[16], pi[16];
#pragma unroll
    for (int j = 0; j < 16; ++j) { pr[j] = (j == k) ? 1.f : 0.f; pi[j] = 0.f; }

    const int ranges[4] = {1, 2, 3, 1};
#pragma unroll
    for (int l = 0; l < NL; ++l) {
#pragma unroll
      for (int q = 0; q < NQ; ++q) {
        float phi = w[l*12 + q*3 + 0];
        float th  = w[l*12 + q*3 + 1];
        float om  = w[l*12 + q*3 + 2];
        float st, ct;  __sincosf(0.5f*th, &st, &ct);
        float spo, cpo; __sincosf(0.5f*(phi+om), &spo, &cpo);
        float smo, cmo; __sincosf(0.5f*(phi-om), &smo, &cmo);
        float ar = cpo*ct,  ai = -spo*ct;
        float br = -cmo*st, bi = -smo*st;
        float dr = cmo*st,  di = -smo*st;
        float er = cpo*ct,  ei = spo*ct;
        int m = 8 >> q;
#pragma unroll
        for (int i0 = 0; i0 < 16; ++i0) {
          if (i0 & m) continue;
          int i1 = i0 | m;
          float x0r = pr[i0], x0i = pi[i0], x1r = pr[i1], x1i = pi[i1];
          pr[i0] = ar*x0r - ai*x0i + br*x1r - bi*x1i;
          pi[i0] = ar*x0i + ai*x0r + br*x1i + bi*x1r;
          pr[i1] = dr*x0r - di*x0i + er*x1r - ei*x1i;
          pi[i1] = dr*x0i + di*x0r + er*x1i + ei*x1r;
        }
      }
      int r = ranges[l];
#pragma unroll
      for (int q = 0; q < NQ; ++q) {
        int mc = 8 >> q;
        int mt = 8 >> ((q + r) & 3);
#pragma unroll
        for (int i = 0; i < 16; ++i) {
          if ((i & mc) && !(i & mt)) {
            int i2 = i | mt;
            float tr = pr[i]; pr[i] = pr[i2]; pr[i2] = tr;
            float ti = pi[i]; pi[i] = pi[i2]; pi[i2] = ti;
          }
        }
      }
    }

    int pc = __popc(k) & 3;
#pragma unroll
    for (int j = 0; j < 16; ++j) {
      float re = pr[j], im = pi[j], re2, im2;
      if      (pc == 0) { re2 =  re; im2 =  im; }
      else if (pc == 1) { re2 =  im; im2 = -re; }
      else if (pc == 2) { re2 = -re; im2 = -im; }
      else              { re2 = -im; im2 =  re; }
      _Float16 h;
      h = (_Float16)re2;
      ws[j*16 + k]            = h;                               // Mh re
      ws[512 + j*16 + k]      = (_Float16)(re2 - (float)h);      // Ml re
      h = (_Float16)im2;
      ws[(16 + j)*16 + k]     = h;                               // Mh im
      ws[512 + (16 + j)*16 + k] = (_Float16)(im2 - (float)h);    // Ml im
    }
  }

  // G matrix rows (threads 0..31 handle rows 0..31; rows >=10 are zero)
  if (k < 32) {
#pragma unroll
    for (int kk = 0; kk < 16; ++kk) {
      float g = 0.f;
      if (k < 10) {
        int j = (kk & 3) + 8 * ((kk >> 2) & 1) + 4 * (kk >> 3);
        g = fcw[k*4 + 0] * ((j & 8) ? -1.f : 1.f)
          + fcw[k*4 + 1] * ((j & 4) ? -1.f : 1.f)
          + fcw[k*4 + 2] * ((j & 2) ? -1.f : 1.f)
          + fcw[k*4 + 3] * ((j & 1) ? -1.f : 1.f);
      }
      _Float16 h = (_Float16)g;
      ws[1024 + k*16 + kk] = h;
      ws[1536 + k*16 + kk] = (_Float16)(g - (float)h);
    }
  }
}

#define ITERS 8

// ---------------------------------------------------------------------------
// Main: per wave-iter 32 samples, ITERS iters fully unrolled with ALL x
// loads issued up front (8 dwordx4 in flight -> HBM latency paid once per
// wave, compute of iter k overlaps residual latency of k+1..).
//   MFMA#1 (x2 split-A): psi[32] = M[32x16] . r[16]
//   probs -> f16 (B-layout matches C-layout automatically)
//   MFMA#2 (x2 split-A): out[10] = Gp[10x16] . p[16] (+bias in acc-init)
//   direct predicated float2 stores (wave region contiguous, fully dirtied)
// ---------------------------------------------------------------------------
__global__ __launch_bounds__(256) void qnn_main(
    const float4* __restrict__ x,     // [B]
    const f16x8*  __restrict__ W8,    // ws: Mh|Ml|Gh|Gl, 64 f16x8 each
    const float*  __restrict__ fcb,   // [10]
    float*        __restrict__ out,   // [B*10]
    int nB)
{
  int t    = threadIdx.x;
  int lane = t & 63;
  int wv   = t >> 6;
  int col  = lane & 31;
  int hi   = lane >> 5;

  int fr = (lane & 31) * 2 + hi;
  f16x8 Ahi = W8[fr];
  f16x8 Alo = W8[64 + fr];
  f16x8 Ghi = W8[128 + fr];
  f16x8 Glo = W8[192 + fr];

  // bias regs: acc2 rows for this lane: hi=0 -> {0,1,2,3,8,9}, hi=1 -> {4,5,6,7}
  int o0 = hi * 4;
  float b0 = fcb[o0 + 0], b1 = fcb[o0 + 1], b2 = fcb[o0 + 2], b3 = fcb[o0 + 3];
  float b4 = hi ? 0.f : fcb[8];
  float b5 = hi ? 0.f : fcb[9];

  int sbase = blockIdx.x * (ITERS * 128) + wv * 32 + col;

  // prefetch all ITERS x-values (independent loads, all in flight)
  float4 xs[ITERS];
#pragma unroll
  for (int it = 0; it < ITERS; ++it) {
    int s = sbase + it * 128;
    xs[it] = x[(s < nB) ? s : 0];
  }

#pragma unroll
  for (int it = 0; it < ITERS; ++it) {
    int s = sbase + it * 128;
    float4 xv = xs[it];

    // cs0 = hi ? sin(x0/2) : cos(x0/2)
    float cs0 = __sinf(fmaf(0.5f, xv.x, hi ? 0.f : 1.57079632679f));
    float s1, c1, s2, c2, s3, c3;
    __sincosf(0.5f * xv.y, &s1, &c1);
    __sincosf(0.5f * xv.z, &s2, &c2);
    __sincosf(0.5f * xv.w, &s3, &c3);

    float a0 = cs0 * c1, a1 = cs0 * s1;
    float w0 = c2 * c3, w1 = c2 * s3, w2 = s2 * c3, w3 = s2 * s3;
    f16x8 Bf;
    Bf[0] = (_Float16)(a0 * w0); Bf[1] = (_Float16)(a0 * w1);
    Bf[2] = (_Float16)(a0 * w2); Bf[3] = (_Float16)(a0 * w3);
    Bf[4] = (_Float16)(a1 * w0); Bf[5] = (_Float16)(a1 * w1);
    Bf[6] = (_Float16)(a1 * w2); Bf[7] = (_Float16)(a1 * w3);

    f32x16 acc = {0.f,0.f,0.f,0.f,0.f,0.f,0.f,0.f,
                  0.f,0.f,0.f,0.f,0.f,0.f,0.f,0.f};
    acc = __builtin_amdgcn_mfma_f32_32x32x16_f16(Ahi, Bf, acc, 0, 0, 0);
    acc = __builtin_amdgcn_mfma_f32_32x32x16_f16(Alo, Bf, acc, 0, 0, 0);

    // probs: reg jj (re) pairs with reg jj+8 (im)
    f16x8 Bp;
    Bp[0] = (_Float16)fmaf(acc[0], acc[0], acc[8]  * acc[8]);
    Bp[1] = (_Float16)fmaf(acc[1], acc[1], acc[9]  * acc[9]);
    Bp[2] = (_Float16)fmaf(acc[2], acc[2], acc[10] * acc[10]);
    Bp[3] = (_Float16)fmaf(acc[3], acc[3], acc[11] * acc[11]);
    Bp[4] = (_Float16)fmaf(acc[4], acc[4], acc[12] * acc[12]);
    Bp[5] = (_Float16)fmaf(acc[5], acc[5], acc[13] * acc[13]);
    Bp[6] = (_Float16)fmaf(acc[6], acc[6], acc[14] * acc[14]);
    Bp[7] = (_Float16)fmaf(acc[7], acc[7], acc[15] * acc[15]);

    f32x16 acc2 = {b0, b1, b2, b3, b4, b5, 0.f, 0.f,
                   0.f, 0.f, 0.f, 0.f, 0.f, 0.f, 0.f, 0.f};
    acc2 = __builtin_amdgcn_mfma_f32_32x32x16_f16(Ghi, Bp, acc2, 0, 0, 0);
    acc2 = __builtin_amdgcn_mfma_f32_32x32x16_f16(Glo, Bp, acc2, 0, 0, 0);

    if (s < nB) {
      float* op = out + (size_t)s * 10 + o0;   // 8B-aligned
      float2 v01; v01.x = acc2[0]; v01.y = acc2[1];
      float2 v23; v23.x = acc2[2]; v23.y = acc2[3];
      *(float2*)(op + 0) = v01;
      *(float2*)(op + 2) = v23;
      if (!hi) {
        float2 v89; v89.x = acc2[4]; v89.y = acc2[5];
        *(float2*)(out + (size_t)s * 10 + 8) = v89;
      }
    }
  }
}

extern "C" void kernel_launch(void* const* d_in, const int* in_sizes, int n_in,
                              void* d_out, int out_size, void* d_ws, size_t ws_size,
                              hipStream_t stream) {
  const float* x   = (const float*)d_in[0];
  const float* w   = (const float*)d_in[1];
  const float* fcw = (const float*)d_in[2];
  const float* fcb = (const float*)d_in[3];
  float* out = (float*)d_out;
  _Float16* ws = (_Float16*)d_ws;   // 2048 f16 = 4 KB
  int nB = in_sizes[0] / 4;

  hipLaunchKernelGGL(qnn_precompute, dim3(1), dim3(64), 0, stream, w, fcw, ws);

  int nblk = (nB + 128 * ITERS - 1) / (128 * ITERS);
  hipLaunchKernelGGL(qnn_main, dim3(nblk), dim3(256), 0, stream,
                     (const float4*)x, (const f16x8*)ws, fcb, out, nB);
}